// Round 6
// baseline (158.122 us; speedup 1.0000x reference)
//
#include <hip/hip_runtime.h>

typedef short short8 __attribute__((ext_vector_type(8)));
typedef short short4v __attribute__((ext_vector_type(4)));
typedef float f32x4 __attribute__((ext_vector_type(4)));
typedef __bf16 bf16x8 __attribute__((ext_vector_type(8)));
typedef _Float16 half4 __attribute__((ext_vector_type(4)));
typedef _Float16 half2v __attribute__((ext_vector_type(2)));

__device__ __forceinline__ short f2bf(float x) {
  unsigned u = __builtin_bit_cast(unsigned, x);
  u += 0x7fffu + ((u >> 16) & 1u);   // round-to-nearest-even
  return (short)(u >> 16);
}

__device__ __forceinline__ f32x4 mfma16(short8 a, short8 b, f32x4 c) {
  return __builtin_amdgcn_mfma_f32_16x16x32_bf16(
      __builtin_bit_cast(bf16x8, a), __builtin_bit_cast(bf16x8, b), c, 0, 0, 0);
}

// async global->LDS, 16B per lane; lds is wave-uniform base (lane i writes base+i*16)
__device__ __forceinline__ void async16(void* lds, const void* g) {
  __builtin_amdgcn_global_load_lds(
      (const __attribute__((address_space(1))) unsigned*)g,
      (__attribute__((address_space(3))) unsigned*)lds, 16, 0, 0);
}

// ---------------- conversion ----------------

__global__ __launch_bounds__(256) void cvt_bf16_kernel(
    const float* __restrict__ x, short* __restrict__ y, int n) {
  int i = blockIdx.x * 256 + threadIdx.x;
  if (i < n) y[i] = f2bf(x[i]);
}

// All four weight transposes in one launch (z selects). W:[1280][1280] f32 ->
// BT[n][k] bf16 with optional fused CAPE (P per t in {0,1}):
// BT_t[n][k] = scale * sum_j W[k][(n&~3)+j] * P[t][j][n&3]
__global__ __launch_bounds__(256) void capeT_all_kernel(
    const float* __restrict__ Wq, const float* __restrict__ Wk,
    const float* __restrict__ Wv, const float* __restrict__ Wo,
    const float* __restrict__ p_inv, const float* __restrict__ p_out,
    float qscale, short* __restrict__ BT0, short* __restrict__ BT1,
    short* __restrict__ wo_t) {
  const int ND = 1280, KD = 1280;
  const size_t SEC = (size_t)1280 * 1280;
  int z = blockIdx.z;
  const float* W;
  const float* P;
  float scale = 1.0f;
  short *d0, *d1;
  if (z == 0) { W = Wq; P = p_inv; scale = qscale; d0 = BT0; d1 = BT1; }
  else if (z == 1) { W = Wk; P = p_out; d0 = BT0 + SEC; d1 = BT1 + SEC; }
  else if (z == 2) { W = Wv; P = nullptr; d0 = BT0 + 2 * SEC; d1 = BT1 + 2 * SEC; }
  else { W = Wo; P = nullptr; d0 = wo_t; d1 = nullptr; }

  __shared__ float tile[32][33];
  int bn = blockIdx.x * 32, bk = blockIdx.y * 32;
  int tx = threadIdx.x, ty = threadIdx.y;  // 32 x 8
  for (int i = ty; i < 32; i += 8)
    tile[i][tx] = W[(size_t)(bk + i) * ND + bn + tx];
  __syncthreads();
  for (int c = ty; c < 32; c += 8) {
    float v0, v1;
    if (P) {
      int g = c & ~3, jj = c & 3;
      float a0 = 0.f, a1 = 0.f;
#pragma unroll
      for (int j = 0; j < 4; j++) {
        float wv = tile[tx][g + j];
        a0 += wv * P[j * 4 + jj];
        a1 += wv * P[16 + j * 4 + jj];
      }
      v0 = a0 * scale;
      v1 = a1 * scale;
    } else {
      v0 = v1 = tile[tx][c] * scale;
    }
    size_t o = (size_t)(bn + c) * KD + bk + tx;
    d0[o] = f2bf(v0);
    if (d1) d1[o] = f2bf(v1);
  }
}

// ---------------- GEMM 128x128 (QKV): C = A[M,K] @ BT[N,K]^T ----------
// B selected per M-block (CAPE t). Epilogue scatters into attention layouts.

__global__ __launch_bounds__(256) void gemm128_qkv_kernel(
    const short* __restrict__ A, const short* __restrict__ B0,
    const short* __restrict__ B1, int M, int N, int K,
    short* __restrict__ qb, short* __restrict__ ktl,
    _Float16* __restrict__ vtl) {
  __shared__ __align__(16) short As[2][128][32];
  __shared__ __align__(16) short Bs[2][128][32];
  int tid = threadIdx.x;
  int l = tid & 63, w = tid >> 6;
  int wr = w >> 1, wc = w & 1;
  int lr = l & 15, lg = l >> 4;
  int bm = blockIdx.y * 128, bn = blockIdx.x * 128;
  const short* BT = (bm >= 1024) ? B1 : B0;
  f32x4 acc[4][4] = {};

  auto stage = [&](int b, int k0) {
    const short* ga = A + (size_t)(bm + (tid >> 2)) * K + k0 + (tid & 3) * 8;
    const short* gb = BT + (size_t)(bn + (tid >> 2)) * K + k0 + (tid & 3) * 8;
    char* la = (char*)&As[b][0][0] + w * 1024;
    char* lb = (char*)&Bs[b][0][0] + w * 1024;
    async16(la, ga);
    async16(la + 4096, ga + (size_t)64 * K);
    async16(lb, gb);
    async16(lb + 4096, gb + (size_t)64 * K);
  };

  auto compute = [&](int b) {
    const short* Ab = &As[b][0][0];
    const short* Bb = &Bs[b][0][0];
    short8 af[4], bf_[4];
#pragma unroll
    for (int mi = 0; mi < 4; mi++)
      af[mi] = *(const short8*)(Ab + (wr * 64 + mi * 16 + lr) * 32 + lg * 8);
#pragma unroll
    for (int nj = 0; nj < 4; nj++)
      bf_[nj] = *(const short8*)(Bb + (wc * 64 + nj * 16 + lr) * 32 + lg * 8);
#pragma unroll
    for (int mi = 0; mi < 4; mi++)
#pragma unroll
      for (int nj = 0; nj < 4; nj++)
        acc[mi][nj] = mfma16(af[mi], bf_[nj], acc[mi][nj]);
  };

  int nk = K >> 5;
  stage(0, 0);
  for (int ks = 0; ks < nk; ks += 2) {
    __syncthreads();
    if (ks + 1 < nk) stage(1, (ks + 1) << 5);
    compute(0);
    __syncthreads();
    if (ks + 2 < nk) stage(0, (ks + 2) << 5);
    compute(1);
  }

#pragma unroll
  for (int mi = 0; mi < 4; mi++)
#pragma unroll
    for (int nj = 0; nj < 4; nj++)
#pragma unroll
      for (int i = 0; i < 4; i++) {
        int row = bm + wr * 64 + mi * 16 + lg * 4 + i;
        int col = bn + wc * 64 + nj * 16 + lr;
        float v = acc[mi][nj][i];
        int s = row;
        if (col < 1280) {                       // Q rows
          qb[(((size_t)(col >> 6)) * 2048 + s) * 64 + (col & 63)] = f2bf(v);
        } else if (col < 2560) {                // K tiled + 16B-chunk swizzle
          int cc = col - 1280;
          int h = cc >> 6, d = cc & 63;
          int kt = s >> 6, r = s & 63;
          int kcol = (((d >> 3) ^ (r & 7)) << 3) | (d & 7);
          ktl[(((size_t)h * 32 + kt) * 64 + r) * 64 + kcol] = f2bf(v);
        } else {                                // V [dv][key] tiled + swizzle
          int cc = col - 2560;
          int h = cc >> 6, dv = cc & 63;
          int kt = s >> 6, kk = s & 63;
          int vcol = (((kk >> 2) ^ (dv & 15)) << 2) | (kk & 3);
          vtl[(((size_t)h * 32 + kt) * 64 + dv) * 64 + vcol] = (_Float16)v;
        }
      }
}

// ---------------- GEMM 64x64 (output proj): out = A@BT^T + bias + resid ----

__global__ __launch_bounds__(256) void gemm64_o_kernel(
    const short* __restrict__ A, const short* __restrict__ BT,
    int M, int N, int K, const float* __restrict__ bias,
    const float* __restrict__ resid, float* __restrict__ out) {
  __shared__ __align__(16) short As[2][64][32];
  __shared__ __align__(16) short Bs[2][64][32];
  int tid = threadIdx.x;
  int l = tid & 63, w = tid >> 6;
  int wr = w >> 1, wc = w & 1;
  int lr = l & 15, lg = l >> 4;
  int bm = blockIdx.y * 64, bn = blockIdx.x * 64;
  f32x4 acc[2][2] = {};

  auto stage = [&](int b, int k0) {
    const short* ga = A + (size_t)(bm + (tid >> 2)) * K + k0 + (tid & 3) * 8;
    const short* gb = BT + (size_t)(bn + (tid >> 2)) * K + k0 + (tid & 3) * 8;
    async16((char*)&As[b][0][0] + w * 1024, ga);
    async16((char*)&Bs[b][0][0] + w * 1024, gb);
  };

  auto compute = [&](int b) {
    const short* Ab = &As[b][0][0];
    const short* Bb = &Bs[b][0][0];
    short8 af[2], bf_[2];
#pragma unroll
    for (int mi = 0; mi < 2; mi++)
      af[mi] = *(const short8*)(Ab + (wr * 32 + mi * 16 + lr) * 32 + lg * 8);
#pragma unroll
    for (int nj = 0; nj < 2; nj++)
      bf_[nj] = *(const short8*)(Bb + (wc * 32 + nj * 16 + lr) * 32 + lg * 8);
#pragma unroll
    for (int mi = 0; mi < 2; mi++)
#pragma unroll
      for (int nj = 0; nj < 2; nj++)
        acc[mi][nj] = mfma16(af[mi], bf_[nj], acc[mi][nj]);
  };

  int nk = K >> 5;
  stage(0, 0);
  for (int ks = 0; ks < nk; ks += 2) {
    __syncthreads();
    if (ks + 1 < nk) stage(1, (ks + 1) << 5);
    compute(0);
    __syncthreads();
    if (ks + 2 < nk) stage(0, (ks + 2) << 5);
    compute(1);
  }

#pragma unroll
  for (int mi = 0; mi < 2; mi++)
#pragma unroll
    for (int nj = 0; nj < 2; nj++)
#pragma unroll
      for (int i = 0; i < 4; i++) {
        int row = bm + wr * 32 + mi * 16 + lg * 4 + i;
        int col = bn + wc * 32 + nj * 16 + lr;
        out[(size_t)row * N + col] =
            acc[mi][nj][i] + bias[col] + resid[(size_t)row * N + col];
      }
}

// ---------------- flash attention: 2-wave blocks, LDS K/V, register P -------
__global__ __launch_bounds__(128) void attn_kernel(
    const short* __restrict__ qb, const short* __restrict__ k_tiled,
    const _Float16* __restrict__ v_tiled, short* __restrict__ attn_out) {
  const int S = 2048, HD = 64;
  int h = blockIdx.x;
  int qblk = blockIdx.y;
  int tid = threadIdx.x;
  int w = tid >> 6, l = tid & 63;
  int lr = l & 15, lg = l >> 4;
  int q0 = qblk * 32 + w * 16;

  __shared__ __align__(16) short Kl[2][64][64];
  __shared__ __align__(16) _Float16 Vl[2][64][64];

  const short* qptr = qb + ((size_t)h * S + q0 + lr) * HD;
  short8 qf0 = *(const short8*)(qptr + lg * 8);
  short8 qf1 = *(const short8*)(qptr + 32 + lg * 8);

  auto stageKV = [&](int b, int kt) {
    const short* gk = k_tiled + (((size_t)h * 32 + kt) << 12) + tid * 8;
    const _Float16* gv = v_tiled + (((size_t)h * 32 + kt) << 12) + tid * 8;
    char* lk = (char*)&Kl[b][0][0] + w * 1024;
    char* lv = (char*)&Vl[b][0][0] + w * 1024;
#pragma unroll
    for (int r = 0; r < 4; r++) {
      async16(lk + r * 2048, gk + r * 1024);
      async16(lv + r * 2048, gv + r * 1024);
    }
  };

  float m = -1e30f, lsum = 0.f;
  f32x4 oacc[4] = {};  // O[q=lg*4+i][dv=nb*16+lr]

  auto compute_tile = [&](int buf) {
    const short* Kb = &Kl[buf][0][0];
    const _Float16* Vb = &Vl[buf][0][0];
    f32x4 st[4];
    __builtin_amdgcn_s_setprio(1);
#pragma unroll
    for (int kk = 0; kk < 4; kk++) {
      int r = kk * 16 + lr;
      int sw = r & 7;
      short8 kf0 = *(const short8*)(Kb + r * 64 + ((lg ^ sw) << 3));
      short8 kf1 = *(const short8*)(Kb + r * 64 + (((4 + lg) ^ sw) << 3));
      f32x4 s0 = {};
      s0 = mfma16(kf0, qf0, s0);
      s0 = mfma16(kf1, qf1, s0);
      st[kk] = s0;
    }
    __builtin_amdgcn_s_setprio(0);
    float m0 = fmaxf(fmaxf(st[0][0], st[0][1]), fmaxf(st[0][2], st[0][3]));
    float m1 = fmaxf(fmaxf(st[1][0], st[1][1]), fmaxf(st[1][2], st[1][3]));
    float m2 = fmaxf(fmaxf(st[2][0], st[2][1]), fmaxf(st[2][2], st[2][3]));
    float m3 = fmaxf(fmaxf(st[3][0], st[3][1]), fmaxf(st[3][2], st[3][3]));
    float tm = fmaxf(fmaxf(m0, m1), fmaxf(m2, m3));
    tm = fmaxf(tm, __shfl_xor(tm, 16));
    tm = fmaxf(tm, __shfl_xor(tm, 32));
    if (!__all(tm <= m + 8.0f)) {  // defer-rescale (T13)
      float mnew = fmaxf(m, tm);
      float fac = __builtin_amdgcn_exp2f(m - mnew);
      lsum *= fac;
#pragma unroll
      for (int i = 0; i < 4; i++) {
        float fi = __shfl(fac, lg * 4 + i);
#pragma unroll
        for (int nb = 0; nb < 4; nb++) oacc[nb][i] *= fi;
      }
      m = mnew;
    }
    half4 pf[4];
    float ps[4];
#pragma unroll
    for (int kk = 0; kk < 4; kk++) {
      float p0 = __builtin_amdgcn_exp2f(st[kk][0] - m);
      float p1 = __builtin_amdgcn_exp2f(st[kk][1] - m);
      float p2 = __builtin_amdgcn_exp2f(st[kk][2] - m);
      float p3 = __builtin_amdgcn_exp2f(st[kk][3] - m);
      half2v lo = __builtin_bit_cast(half2v, __builtin_amdgcn_cvt_pkrtz(p0, p1));
      half2v hi = __builtin_bit_cast(half2v, __builtin_amdgcn_cvt_pkrtz(p2, p3));
      pf[kk][0] = lo[0]; pf[kk][1] = lo[1];
      pf[kk][2] = hi[0]; pf[kk][3] = hi[1];
      ps[kk] = (p0 + p1) + (p2 + p3);
    }
    float psum = (ps[0] + ps[1]) + (ps[2] + ps[3]);
    psum += __shfl_xor(psum, 16);
    psum += __shfl_xor(psum, 32);
    lsum += psum;
#pragma unroll
    for (int kk = 0; kk < 4; kk++) {
      half4 vf[4];
#pragma unroll
      for (int nb = 0; nb < 4; nb++) {
        int dv = nb * 16 + lr;
        vf[nb] = *(const half4*)(Vb + dv * 64 + ((((kk << 2) + lg) ^ lr) << 2));
      }
      __builtin_amdgcn_s_setprio(1);
#pragma unroll
      for (int nb = 0; nb < 4; nb++)
        oacc[nb] = __builtin_amdgcn_mfma_f32_16x16x16f16(pf[kk], vf[nb], oacc[nb], 0, 0, 0);
      __builtin_amdgcn_s_setprio(0);
    }
  };

  stageKV(0, 0);
  for (int kt2 = 0; kt2 < 32; kt2 += 2) {
    __syncthreads();
    if (kt2 + 1 < 32) stageKV(1, kt2 + 1);
    compute_tile(0);
    __syncthreads();
    if (kt2 + 2 < 32) stageKV(0, kt2 + 2);
    compute_tile(1);
  }

#pragma unroll
  for (int i = 0; i < 4; i++) {
    float li = __shfl(lsum, lg * 4 + i);
    float inv = 1.0f / li;
    int row = q0 + lg * 4 + i;
#pragma unroll
    for (int nb = 0; nb < 4; nb++)
      attn_out[(size_t)row * 1280 + h * 64 + nb * 16 + lr] = f2bf(oacc[nb][i] * inv);
  }
}

// ---------------- launch ----------------

extern "C" void kernel_launch(void* const* d_in, const int* in_sizes, int n_in,
                              void* d_out, int out_size, void* d_ws, size_t ws_size,
                              hipStream_t stream) {
  const float* hs = (const float*)d_in[0];
  const float* p_out = (const float*)d_in[1];
  const float* p_inv = (const float*)d_in[2];
  const float* Wq = (const float*)d_in[3];
  const float* Wk = (const float*)d_in[4];
  const float* Wv = (const float*)d_in[5];
  const float* Wo = (const float*)d_in[6];
  const float* bo = (const float*)d_in[7];
  float* out = (float*)d_out;
  char* ws = (char*)d_ws;

  // workspace layout (bytes)
  short* hs_bf = (short*)(ws + 0);                  //  5,242,880
  short* BT0 = (short*)(ws + 5242880);              //  9,830,400
  short* BT1 = (short*)(ws + 15073280);             //  9,830,400
  short* wo_t = (short*)(ws + 24903680);            //  3,276,800
  short* q_bf = (short*)(ws + 28180480);            //  5,242,880
  short* k_tiled = (short*)(ws + 33423360);         //  5,242,880
  _Float16* v_tiled = (_Float16*)(ws + 38666240);   //  5,242,880
  short* attn_bf = (short*)(ws + 43909120);         //  5,242,880 (ends 49,152,000)

  const float QSCALE = 0.125f * 1.44269504f;  // hd^-0.5 * log2(e)
  const int n_hs = 2048 * 1280;
  cvt_bf16_kernel<<<(n_hs + 255) / 256, 256, 0, stream>>>(hs, hs_bf, n_hs);

  capeT_all_kernel<<<dim3(40, 40, 4), dim3(32, 8), 0, stream>>>(
      Wq, Wk, Wv, Wo, p_inv, p_out, QSCALE, BT0, BT1, wo_t);

  gemm128_qkv_kernel<<<dim3(30, 16), 256, 0, stream>>>(
      hs_bf, BT0, BT1, 2048, 3840, 1280, q_bf, k_tiled, v_tiled);

  attn_kernel<<<dim3(20, 64), 128, 0, stream>>>(q_bf, k_tiled, v_tiled, attn_bf);

  gemm64_o_kernel<<<dim3(20, 32), 256, 0, stream>>>(
      attn_bf, wo_t, 2048, 1280, 1280, bo, hs, out);
}

// Round 8
// 124.950 us; speedup vs baseline: 1.2655x; 1.2655x over previous
//
#include <hip/hip_runtime.h>

typedef short short8 __attribute__((ext_vector_type(8)));
typedef short short4v __attribute__((ext_vector_type(4)));
typedef float f32x4 __attribute__((ext_vector_type(4)));
typedef float float4v __attribute__((ext_vector_type(4)));
typedef __bf16 bf16x8 __attribute__((ext_vector_type(8)));
typedef _Float16 half4 __attribute__((ext_vector_type(4)));
typedef _Float16 half2v __attribute__((ext_vector_type(2)));

__device__ __forceinline__ short f2bf(float x) {
  unsigned u = __builtin_bit_cast(unsigned, x);
  u += 0x7fffu + ((u >> 16) & 1u);   // round-to-nearest-even
  return (short)(u >> 16);
}

__device__ __forceinline__ f32x4 mfma16(short8 a, short8 b, f32x4 c) {
  return __builtin_amdgcn_mfma_f32_16x16x32_bf16(
      __builtin_bit_cast(bf16x8, a), __builtin_bit_cast(bf16x8, b), c, 0, 0, 0);
}

// async global->LDS, 16B per lane; lds is wave-uniform base (lane i writes base+i*16)
__device__ __forceinline__ void async16(void* lds, const void* g) {
  __builtin_amdgcn_global_load_lds(
      (const __attribute__((address_space(1))) unsigned*)g,
      (__attribute__((address_space(3))) unsigned*)lds, 16, 0, 0);
}

// ---------------- conversion ----------------

__global__ __launch_bounds__(256) void cvt_bf16_kernel(
    const float* __restrict__ x, short* __restrict__ y, int n4) {
  int i = blockIdx.x * 256 + threadIdx.x;
  if (i < n4) {
    float4v v = *(const float4v*)(x + (size_t)i * 4);
    short4v o;
#pragma unroll
    for (int j = 0; j < 4; j++) o[j] = f2bf(v[j]);
    *(short4v*)(y + (size_t)i * 4) = o;
  }
}

// All four weight transposes in one launch (z selects). W:[1280][1280] f32 ->
// BT[n][k] bf16 with optional fused CAPE (P per t in {0,1}):
// BT_t[n][k] = scale * sum_j W[k][(n&~3)+j] * P[t][j][n&3]
__global__ __launch_bounds__(256) void capeT_all_kernel(
    const float* __restrict__ Wq, const float* __restrict__ Wk,
    const float* __restrict__ Wv, const float* __restrict__ Wo,
    const float* __restrict__ p_inv, const float* __restrict__ p_out,
    float qscale, short* __restrict__ BT0, short* __restrict__ BT1,
    short* __restrict__ wo_t) {
  const int ND = 1280, KD = 1280;
  const size_t SEC = (size_t)1280 * 1280;
  int z = blockIdx.z;
  const float* W;
  const float* P;
  float scale = 1.0f;
  short *d0, *d1;
  if (z == 0) { W = Wq; P = p_inv; scale = qscale; d0 = BT0; d1 = BT1; }
  else if (z == 1) { W = Wk; P = p_out; d0 = BT0 + SEC; d1 = BT1 + SEC; }
  else if (z == 2) { W = Wv; P = nullptr; d0 = BT0 + 2 * SEC; d1 = BT1 + 2 * SEC; }
  else { W = Wo; P = nullptr; d0 = wo_t; d1 = nullptr; }

  __shared__ float tile[32][33];
  int bn = blockIdx.x * 32, bk = blockIdx.y * 32;
  int tx = threadIdx.x, ty = threadIdx.y;  // 32 x 8
  for (int i = ty; i < 32; i += 8)
    tile[i][tx] = W[(size_t)(bk + i) * ND + bn + tx];
  __syncthreads();
  for (int c = ty; c < 32; c += 8) {
    float v0, v1;
    if (P) {
      int g = c & ~3, jj = c & 3;
      float a0 = 0.f, a1 = 0.f;
#pragma unroll
      for (int j = 0; j < 4; j++) {
        float wv = tile[tx][g + j];
        a0 += wv * P[j * 4 + jj];
        a1 += wv * P[16 + j * 4 + jj];
      }
      v0 = a0 * scale;
      v1 = a1 * scale;
    } else {
      v0 = v1 = tile[tx][c] * scale;
    }
    size_t o = (size_t)(bn + c) * KD + bk + tx;
    d0[o] = f2bf(v0);
    if (d1) d1[o] = f2bf(v1);
  }
}

// ---------------- GEMM 128x128 (QKV): C = A[M,K] @ BT[N,K]^T ----------
// B selected per M-block (CAPE t). Epilogue scatters into attention layouts:
//   Q:  qb[h][s][64]  (row-major)
//   K:  ktl[h][kt][key][64] with 16B-chunk XOR swizzle
//   V:  vtl[h][kt][dv][key] with 8B-granule XOR swizzle (verified r4 layout)

__global__ __launch_bounds__(256) void gemm128_qkv_kernel(
    const short* __restrict__ A, const short* __restrict__ B0,
    const short* __restrict__ B1, int M, int N, int K,
    short* __restrict__ qb, short* __restrict__ ktl,
    _Float16* __restrict__ vtl) {
  __shared__ __align__(16) short As[2][128][32];
  __shared__ __align__(16) short Bs[2][128][32];
  int tid = threadIdx.x;
  int l = tid & 63, w = tid >> 6;
  int wr = w >> 1, wc = w & 1;
  int lr = l & 15, lg = l >> 4;
  int bm = blockIdx.y * 128, bn = blockIdx.x * 128;
  const short* BT = (bm >= 1024) ? B1 : B0;
  f32x4 acc[4][4] = {};

  auto stage = [&](int b, int k0) {
    const short* ga = A + (size_t)(bm + (tid >> 2)) * K + k0 + (tid & 3) * 8;
    const short* gb = BT + (size_t)(bn + (tid >> 2)) * K + k0 + (tid & 3) * 8;
    char* la = (char*)&As[b][0][0] + w * 1024;
    char* lb = (char*)&Bs[b][0][0] + w * 1024;
    async16(la, ga);
    async16(la + 4096, ga + (size_t)64 * K);
    async16(lb, gb);
    async16(lb + 4096, gb + (size_t)64 * K);
  };

  auto compute = [&](int b) {
    const short* Ab = &As[b][0][0];
    const short* Bb = &Bs[b][0][0];
    short8 af[4], bf_[4];
#pragma unroll
    for (int mi = 0; mi < 4; mi++)
      af[mi] = *(const short8*)(Ab + (wr * 64 + mi * 16 + lr) * 32 + lg * 8);
#pragma unroll
    for (int nj = 0; nj < 4; nj++)
      bf_[nj] = *(const short8*)(Bb + (wc * 64 + nj * 16 + lr) * 32 + lg * 8);
#pragma unroll
    for (int mi = 0; mi < 4; mi++)
#pragma unroll
      for (int nj = 0; nj < 4; nj++)
        acc[mi][nj] = mfma16(af[mi], bf_[nj], acc[mi][nj]);
  };

  int nk = K >> 5;
  stage(0, 0);
  for (int ks = 0; ks < nk; ks += 2) {
    __syncthreads();
    if (ks + 1 < nk) stage(1, (ks + 1) << 5);
    compute(0);
    __syncthreads();
    if (ks + 2 < nk) stage(0, (ks + 2) << 5);
    compute(1);
  }

#pragma unroll
  for (int mi = 0; mi < 4; mi++)
#pragma unroll
    for (int nj = 0; nj < 4; nj++)
#pragma unroll
      for (int i = 0; i < 4; i++) {
        int row = bm + wr * 64 + mi * 16 + lg * 4 + i;
        int col = bn + wc * 64 + nj * 16 + lr;
        float v = acc[mi][nj][i];
        int s = row;
        if (col < 1280) {                       // Q rows
          qb[(((size_t)(col >> 6)) * 2048 + s) * 64 + (col & 63)] = f2bf(v);
        } else if (col < 2560) {                // K tiled + 16B-chunk swizzle
          int cc = col - 1280;
          int h = cc >> 6, d = cc & 63;
          int kt = s >> 6, r = s & 63;
          int kcol = (((d >> 3) ^ (r & 7)) << 3) | (d & 7);
          ktl[(((size_t)h * 32 + kt) * 64 + r) * 64 + kcol] = f2bf(v);
        } else {                                // V [dv][key] tiled + swizzle
          int cc = col - 2560;
          int h = cc >> 6, dv = cc & 63;
          int kt = s >> 6, kk = s & 63;
          int vcol = (((kk >> 2) ^ (dv & 15)) << 2) | (kk & 3);
          vtl[(((size_t)h * 32 + kt) * 64 + dv) * 64 + vcol] = (_Float16)v;
        }
      }
}

// ---------------- GEMM 64x64 (output proj): out = A@BT^T + bias + resid ----

__global__ __launch_bounds__(256) void gemm64_o_kernel(
    const short* __restrict__ A, const short* __restrict__ BT,
    int M, int N, int K, const float* __restrict__ bias,
    const float* __restrict__ resid, float* __restrict__ out) {
  __shared__ __align__(16) short As[2][64][32];
  __shared__ __align__(16) short Bs[2][64][32];
  int tid = threadIdx.x;
  int l = tid & 63, w = tid >> 6;
  int wr = w >> 1, wc = w & 1;
  int lr = l & 15, lg = l >> 4;
  int bm = blockIdx.y * 64, bn = blockIdx.x * 64;
  f32x4 acc[2][2] = {};

  auto stage = [&](int b, int k0) {
    const short* ga = A + (size_t)(bm + (tid >> 2)) * K + k0 + (tid & 3) * 8;
    const short* gb = BT + (size_t)(bn + (tid >> 2)) * K + k0 + (tid & 3) * 8;
    async16((char*)&As[b][0][0] + w * 1024, ga);
    async16((char*)&Bs[b][0][0] + w * 1024, gb);
  };

  auto compute = [&](int b) {
    const short* Ab = &As[b][0][0];
    const short* Bb = &Bs[b][0][0];
    short8 af[2], bf_[2];
#pragma unroll
    for (int mi = 0; mi < 2; mi++)
      af[mi] = *(const short8*)(Ab + (wr * 32 + mi * 16 + lr) * 32 + lg * 8);
#pragma unroll
    for (int nj = 0; nj < 2; nj++)
      bf_[nj] = *(const short8*)(Bb + (wc * 32 + nj * 16 + lr) * 32 + lg * 8);
#pragma unroll
    for (int mi = 0; mi < 2; mi++)
#pragma unroll
      for (int nj = 0; nj < 2; nj++)
        acc[mi][nj] = mfma16(af[mi], bf_[nj], acc[mi][nj]);
  };

  int nk = K >> 5;
  stage(0, 0);
  for (int ks = 0; ks < nk; ks += 2) {
    __syncthreads();
    if (ks + 1 < nk) stage(1, (ks + 1) << 5);
    compute(0);
    __syncthreads();
    if (ks + 2 < nk) stage(0, (ks + 2) << 5);
    compute(1);
  }

#pragma unroll
  for (int mi = 0; mi < 2; mi++)
#pragma unroll
    for (int nj = 0; nj < 2; nj++)
#pragma unroll
      for (int i = 0; i < 4; i++) {
        int row = bm + wr * 32 + mi * 16 + lg * 4 + i;
        int col = bn + wc * 32 + nj * 16 + lr;
        out[(size_t)row * N + col] =
            acc[mi][nj][i] + bias[col] + resid[(size_t)row * N + col];
      }
}

// ---------------- flash attention: 4-wave blocks, LDS K/V, register P -------
__global__ __launch_bounds__(256) void attn_kernel(
    const short* __restrict__ qb, const short* __restrict__ k_tiled,
    const _Float16* __restrict__ v_tiled, short* __restrict__ attn_out) {
  const int S = 2048, HD = 64;
  int h = blockIdx.x;
  int qblk = blockIdx.y;
  int tid = threadIdx.x;
  int w = tid >> 6, l = tid & 63;
  int lr = l & 15, lg = l >> 4;
  int q0 = qblk * 64 + w * 16;

  __shared__ __align__(16) short Kl[2][64][64];
  __shared__ __align__(16) _Float16 Vl[2][64][64];

  const short* qptr = qb + ((size_t)h * S + q0 + lr) * HD;
  short8 qf0 = *(const short8*)(qptr + lg * 8);
  short8 qf1 = *(const short8*)(qptr + 32 + lg * 8);

  auto stageKV = [&](int b, int kt) {
    const short* gk = k_tiled + (((size_t)h * 32 + kt) << 12) + tid * 8;
    const _Float16* gv = v_tiled + (((size_t)h * 32 + kt) << 12) + tid * 8;
    char* lk = (char*)&Kl[b][0][0] + w * 1024;
    char* lv = (char*)&Vl[b][0][0] + w * 1024;
    async16(lk, gk);
    async16(lk + 4096, gk + 2048);
    async16(lv, gv);
    async16(lv + 4096, gv + 2048);
  };

  float m = -1e30f, lsum = 0.f;  // lsum: per-lane partial (cross-lane reduce at end)
  f32x4 oacc[4] = {};  // O[q=lg*4+i][dv=nb*16+lr]

  auto compute_tile = [&](int buf) {
    const short* Kb = &Kl[buf][0][0];
    const _Float16* Vb = &Vl[buf][0][0];
    f32x4 st[4];
    __builtin_amdgcn_s_setprio(1);
#pragma unroll
    for (int kk = 0; kk < 4; kk++) {
      int r = kk * 16 + lr;
      int sw = r & 7;
      short8 kf0 = *(const short8*)(Kb + r * 64 + ((lg ^ sw) << 3));
      short8 kf1 = *(const short8*)(Kb + r * 64 + (((4 + lg) ^ sw) << 3));
      f32x4 s0 = {};
      s0 = mfma16(kf0, qf0, s0);
      s0 = mfma16(kf1, qf1, s0);
      st[kk] = s0;
    }
    __builtin_amdgcn_s_setprio(0);
    float m0 = fmaxf(fmaxf(st[0][0], st[0][1]), fmaxf(st[0][2], st[0][3]));
    float m1 = fmaxf(fmaxf(st[1][0], st[1][1]), fmaxf(st[1][2], st[1][3]));
    float m2 = fmaxf(fmaxf(st[2][0], st[2][1]), fmaxf(st[2][2], st[2][3]));
    float m3 = fmaxf(fmaxf(st[3][0], st[3][1]), fmaxf(st[3][2], st[3][3]));
    float tm = fmaxf(fmaxf(m0, m1), fmaxf(m2, m3));
    tm = fmaxf(tm, __shfl_xor(tm, 16));
    tm = fmaxf(tm, __shfl_xor(tm, 32));
    if (!__all(tm <= m + 8.0f)) {  // defer-rescale (T13)
      float mnew = fmaxf(m, tm);
      float fac = __builtin_amdgcn_exp2f(m - mnew);
      lsum *= fac;
#pragma unroll
      for (int i = 0; i < 4; i++) {
        float fi = __shfl(fac, lg * 4 + i);
#pragma unroll
        for (int nb = 0; nb < 4; nb++) oacc[nb][i] *= fi;
      }
      m = mnew;
    }
    half4 pf[4];
    float ps[4];
#pragma unroll
    for (int kk = 0; kk < 4; kk++) {
      float p0 = __builtin_amdgcn_exp2f(st[kk][0] - m);
      float p1 = __builtin_amdgcn_exp2f(st[kk][1] - m);
      float p2 = __builtin_amdgcn_exp2f(st[kk][2] - m);
      float p3 = __builtin_amdgcn_exp2f(st[kk][3] - m);
      half2v lo = __builtin_bit_cast(half2v, __builtin_amdgcn_cvt_pkrtz(p0, p1));
      half2v hi = __builtin_bit_cast(half2v, __builtin_amdgcn_cvt_pkrtz(p2, p3));
      pf[kk][0] = lo[0]; pf[kk][1] = lo[1];
      pf[kk][2] = hi[0]; pf[kk][3] = hi[1];
      ps[kk] = (p0 + p1) + (p2 + p3);
    }
    lsum += (ps[0] + ps[1]) + (ps[2] + ps[3]);
#pragma unroll
    for (int kk = 0; kk < 4; kk++) {
      half4 vf[4];
#pragma unroll
      for (int nb = 0; nb < 4; nb++) {
        int dv = nb * 16 + lr;
        vf[nb] = *(const half4*)(Vb + dv * 64 + ((((kk << 2) + lg) ^ lr) << 2));
      }
      __builtin_amdgcn_s_setprio(1);
#pragma unroll
      for (int nb = 0; nb < 4; nb++)
        oacc[nb] = __builtin_amdgcn_mfma_f32_16x16x16f16(pf[kk], vf[nb], oacc[nb], 0, 0, 0);
      __builtin_amdgcn_s_setprio(0);
    }
  };

  stageKV(0, 0);
  for (int kt2 = 0; kt2 < 32; kt2 += 2) {
    __syncthreads();
    if (kt2 + 1 < 32) stageKV(1, kt2 + 1);
    compute_tile(0);
    __syncthreads();
    if (kt2 + 2 < 32) stageKV(0, kt2 + 2);
    compute_tile(1);
  }

  // final cross-lane row-sum reduce (deferred from per-tile)
  lsum += __shfl_xor(lsum, 16);
  lsum += __shfl_xor(lsum, 32);

#pragma unroll
  for (int i = 0; i < 4; i++) {
    float li = __shfl(lsum, lg * 4 + i);
    float inv = 1.0f / li;
    int row = q0 + lg * 4 + i;
#pragma unroll
    for (int nb = 0; nb < 4; nb++)
      attn_out[(size_t)row * 1280 + h * 64 + nb * 16 + lr] = f2bf(oacc[nb][i] * inv);
  }
}

// ---------------- launch ----------------

extern "C" void kernel_launch(void* const* d_in, const int* in_sizes, int n_in,
                              void* d_out, int out_size, void* d_ws, size_t ws_size,
                              hipStream_t stream) {
  const float* hs = (const float*)d_in[0];
  const float* p_out = (const float*)d_in[1];
  const float* p_inv = (const float*)d_in[2];
  const float* Wq = (const float*)d_in[3];
  const float* Wk = (const float*)d_in[4];
  const float* Wv = (const float*)d_in[5];
  const float* Wo = (const float*)d_in[6];
  const float* bo = (const float*)d_in[7];
  float* out = (float*)d_out;
  char* ws = (char*)d_ws;

  // workspace layout (bytes)
  short* hs_bf = (short*)(ws + 0);                  //  5,242,880
  short* BT0 = (short*)(ws + 5242880);              //  9,830,400
  short* BT1 = (short*)(ws + 15073280);             //  9,830,400
  short* wo_t = (short*)(ws + 24903680);            //  3,276,800
  short* q_bf = (short*)(ws + 28180480);            //  5,242,880
  short* k_tiled = (short*)(ws + 33423360);         //  5,242,880
  _Float16* v_tiled = (_Float16*)(ws + 38666240);   //  5,242,880
  short* attn_bf = (short*)(ws + 43909120);         //  5,242,880 (ends 49,152,000)

  const float QSCALE = 0.125f * 1.44269504f;  // hd^-0.5 * log2(e)
  const int n4 = 2048 * 1280 / 4;
  cvt_bf16_kernel<<<(n4 + 255) / 256, 256, 0, stream>>>(hs, hs_bf, n4);

  capeT_all_kernel<<<dim3(40, 40, 4), dim3(32, 8), 0, stream>>>(
      Wq, Wk, Wv, Wo, p_inv, p_out, QSCALE, BT0, BT1, wo_t);

  gemm128_qkv_kernel<<<dim3(30, 16), 256, 0, stream>>>(
      hs_bf, BT0, BT1, 2048, 3840, 1280, q_bf, k_tiled, v_tiled);

  attn_kernel<<<dim3(20, 32), 256, 0, stream>>>(q_bf, k_tiled, v_tiled, attn_bf);

  gemm64_o_kernel<<<dim3(20, 32), 256, 0, stream>>>(
      attn_bf, wo_t, 2048, 1280, 1280, bo, hs, out);
}

// Round 9
// 121.457 us; speedup vs baseline: 1.3019x; 1.0288x over previous
//
#include <hip/hip_runtime.h>

typedef short short8 __attribute__((ext_vector_type(8)));
typedef short short4v __attribute__((ext_vector_type(4)));
typedef float f32x4 __attribute__((ext_vector_type(4)));
typedef float float4v __attribute__((ext_vector_type(4)));
typedef __bf16 bf16x8 __attribute__((ext_vector_type(8)));
typedef _Float16 half4 __attribute__((ext_vector_type(4)));
typedef _Float16 half2v __attribute__((ext_vector_type(2)));

__device__ __forceinline__ short f2bf(float x) {
  unsigned u = __builtin_bit_cast(unsigned, x);
  u += 0x7fffu + ((u >> 16) & 1u);   // round-to-nearest-even
  return (short)(u >> 16);
}

__device__ __forceinline__ f32x4 mfma16(short8 a, short8 b, f32x4 c) {
  return __builtin_amdgcn_mfma_f32_16x16x32_bf16(
      __builtin_bit_cast(bf16x8, a), __builtin_bit_cast(bf16x8, b), c, 0, 0, 0);
}

// async global->LDS, 16B per lane; lds is wave-uniform base (lane i writes base+i*16)
__device__ __forceinline__ void async16(void* lds, const void* g) {
  __builtin_amdgcn_global_load_lds(
      (const __attribute__((address_space(1))) unsigned*)g,
      (__attribute__((address_space(3))) unsigned*)lds, 16, 0, 0);
}

// ---------------- fused weight-transpose + CAPE + input cvt ----------------
// z=0..3: W transposes (Wq/Wk/Wv/Wo) as before; z=4: hs f32->bf16 cvt.
__global__ __launch_bounds__(256) void capeT_all_kernel(
    const float* __restrict__ Wq, const float* __restrict__ Wk,
    const float* __restrict__ Wv, const float* __restrict__ Wo,
    const float* __restrict__ p_inv, const float* __restrict__ p_out,
    float qscale, short* __restrict__ BT0, short* __restrict__ BT1,
    short* __restrict__ wo_t, const float* __restrict__ hs,
    short* __restrict__ hs_bf) {
  const int ND = 1280, KD = 1280;
  const size_t SEC = (size_t)1280 * 1280;
  int z = blockIdx.z;
  int tx = threadIdx.x, ty = threadIdx.y;  // 32 x 8
  if (z == 4) {  // hs conversion: 1600 blocks * 256 threads * 2 float4
    int t = ty * 32 + tx;
    int base = ((blockIdx.y * 40 + blockIdx.x) * 256 + t) * 2;
    const int n4 = 2048 * 1280 / 4;
#pragma unroll
    for (int r = 0; r < 2; r++) {
      int i = base + r;
      if (i < n4) {
        float4v v = *(const float4v*)(hs + (size_t)i * 4);
        short4v o;
#pragma unroll
        for (int j = 0; j < 4; j++) o[j] = f2bf(v[j]);
        *(short4v*)(hs_bf + (size_t)i * 4) = o;
      }
    }
    return;
  }
  const float* W;
  const float* P;
  float scale = 1.0f;
  short *d0, *d1;
  if (z == 0) { W = Wq; P = p_inv; scale = qscale; d0 = BT0; d1 = BT1; }
  else if (z == 1) { W = Wk; P = p_out; d0 = BT0 + SEC; d1 = BT1 + SEC; }
  else if (z == 2) { W = Wv; P = nullptr; d0 = BT0 + 2 * SEC; d1 = BT1 + 2 * SEC; }
  else { W = Wo; P = nullptr; d0 = wo_t; d1 = nullptr; }

  __shared__ float tile[32][33];
  int bn = blockIdx.x * 32, bk = blockIdx.y * 32;
  for (int i = ty; i < 32; i += 8)
    tile[i][tx] = W[(size_t)(bk + i) * ND + bn + tx];
  __syncthreads();
  for (int c = ty; c < 32; c += 8) {
    float v0, v1;
    if (P) {
      int g = c & ~3, jj = c & 3;
      float a0 = 0.f, a1 = 0.f;
#pragma unroll
      for (int j = 0; j < 4; j++) {
        float wv = tile[tx][g + j];
        a0 += wv * P[j * 4 + jj];
        a1 += wv * P[16 + j * 4 + jj];
      }
      v0 = a0 * scale;
      v1 = a1 * scale;
    } else {
      v0 = v1 = tile[tx][c] * scale;
    }
    size_t o = (size_t)(bn + c) * KD + bk + tx;
    d0[o] = f2bf(v0);
    if (d1) d1[o] = f2bf(v1);
  }
}

// ---------------- GEMM 128x128 (QKV): C = A[M,K] @ BT[N,K]^T ----------
// B selected per M-block (CAPE t). Epilogue scatters into attention layouts:
//   Q:  qb[h][s][64]  (row-major)
//   K:  ktl[h][kt][key][64] with 16B-chunk XOR swizzle
//   V:  vtl[h][kt][dv][key] with 8B-granule XOR swizzle

__global__ __launch_bounds__(256) void gemm128_qkv_kernel(
    const short* __restrict__ A, const short* __restrict__ B0,
    const short* __restrict__ B1, int M, int N, int K,
    short* __restrict__ qb, short* __restrict__ ktl,
    _Float16* __restrict__ vtl) {
  __shared__ __align__(16) short As[2][128][32];
  __shared__ __align__(16) short Bs[2][128][32];
  int tid = threadIdx.x;
  int l = tid & 63, w = tid >> 6;
  int wr = w >> 1, wc = w & 1;
  int lr = l & 15, lg = l >> 4;
  int bm = blockIdx.y * 128, bn = blockIdx.x * 128;
  const short* BT = (bm >= 1024) ? B1 : B0;
  f32x4 acc[4][4] = {};

  auto stage = [&](int b, int k0) {
    const short* ga = A + (size_t)(bm + (tid >> 2)) * K + k0 + (tid & 3) * 8;
    const short* gb = BT + (size_t)(bn + (tid >> 2)) * K + k0 + (tid & 3) * 8;
    char* la = (char*)&As[b][0][0] + w * 1024;
    char* lb = (char*)&Bs[b][0][0] + w * 1024;
    async16(la, ga);
    async16(la + 4096, ga + (size_t)64 * K);
    async16(lb, gb);
    async16(lb + 4096, gb + (size_t)64 * K);
  };

  auto compute = [&](int b) {
    const short* Ab = &As[b][0][0];
    const short* Bb = &Bs[b][0][0];
    short8 af[4], bf_[4];
#pragma unroll
    for (int mi = 0; mi < 4; mi++)
      af[mi] = *(const short8*)(Ab + (wr * 64 + mi * 16 + lr) * 32 + lg * 8);
#pragma unroll
    for (int nj = 0; nj < 4; nj++)
      bf_[nj] = *(const short8*)(Bb + (wc * 64 + nj * 16 + lr) * 32 + lg * 8);
#pragma unroll
    for (int mi = 0; mi < 4; mi++)
#pragma unroll
      for (int nj = 0; nj < 4; nj++)
        acc[mi][nj] = mfma16(af[mi], bf_[nj], acc[mi][nj]);
  };

  int nk = K >> 5;
  stage(0, 0);
  for (int ks = 0; ks < nk; ks += 2) {
    __syncthreads();
    if (ks + 1 < nk) stage(1, (ks + 1) << 5);
    compute(0);
    __syncthreads();
    if (ks + 2 < nk) stage(0, (ks + 2) << 5);
    compute(1);
  }

#pragma unroll
  for (int mi = 0; mi < 4; mi++)
#pragma unroll
    for (int nj = 0; nj < 4; nj++)
#pragma unroll
      for (int i = 0; i < 4; i++) {
        int row = bm + wr * 64 + mi * 16 + lg * 4 + i;
        int col = bn + wc * 64 + nj * 16 + lr;
        float v = acc[mi][nj][i];
        int s = row;
        if (col < 1280) {                       // Q rows
          qb[(((size_t)(col >> 6)) * 2048 + s) * 64 + (col & 63)] = f2bf(v);
        } else if (col < 2560) {                // K tiled + 16B-chunk swizzle
          int cc = col - 1280;
          int h = cc >> 6, d = cc & 63;
          int kt = s >> 6, r = s & 63;
          int kcol = (((d >> 3) ^ (r & 7)) << 3) | (d & 7);
          ktl[(((size_t)h * 32 + kt) * 64 + r) * 64 + kcol] = f2bf(v);
        } else {                                // V [dv][key] tiled + swizzle
          int cc = col - 2560;
          int h = cc >> 6, dv = cc & 63;
          int kt = s >> 6, kk = s & 63;
          int vcol = (((kk >> 2) ^ (dv & 15)) << 2) | (kk & 3);
          vtl[(((size_t)h * 32 + kt) * 64 + dv) * 64 + vcol] = (_Float16)v;
        }
      }
}

// ---------------- GEMM 64x64 (output proj): out = A@BT^T + bias + resid ----

__global__ __launch_bounds__(256) void gemm64_o_kernel(
    const short* __restrict__ A, const short* __restrict__ BT,
    int M, int N, int K, const float* __restrict__ bias,
    const float* __restrict__ resid, float* __restrict__ out) {
  __shared__ __align__(16) short As[2][64][32];
  __shared__ __align__(16) short Bs[2][64][32];
  int tid = threadIdx.x;
  int l = tid & 63, w = tid >> 6;
  int wr = w >> 1, wc = w & 1;
  int lr = l & 15, lg = l >> 4;
  int bm = blockIdx.y * 64, bn = blockIdx.x * 64;
  f32x4 acc[2][2] = {};

  auto stage = [&](int b, int k0) {
    const short* ga = A + (size_t)(bm + (tid >> 2)) * K + k0 + (tid & 3) * 8;
    const short* gb = BT + (size_t)(bn + (tid >> 2)) * K + k0 + (tid & 3) * 8;
    async16((char*)&As[b][0][0] + w * 1024, ga);
    async16((char*)&Bs[b][0][0] + w * 1024, gb);
  };

  auto compute = [&](int b) {
    const short* Ab = &As[b][0][0];
    const short* Bb = &Bs[b][0][0];
    short8 af[2], bf_[2];
#pragma unroll
    for (int mi = 0; mi < 2; mi++)
      af[mi] = *(const short8*)(Ab + (wr * 32 + mi * 16 + lr) * 32 + lg * 8);
#pragma unroll
    for (int nj = 0; nj < 2; nj++)
      bf_[nj] = *(const short8*)(Bb + (wc * 32 + nj * 16 + lr) * 32 + lg * 8);
#pragma unroll
    for (int mi = 0; mi < 2; mi++)
#pragma unroll
      for (int nj = 0; nj < 2; nj++)
        acc[mi][nj] = mfma16(af[mi], bf_[nj], acc[mi][nj]);
  };

  int nk = K >> 5;
  stage(0, 0);
  for (int ks = 0; ks < nk; ks += 2) {
    __syncthreads();
    if (ks + 1 < nk) stage(1, (ks + 1) << 5);
    compute(0);
    __syncthreads();
    if (ks + 2 < nk) stage(0, (ks + 2) << 5);
    compute(1);
  }

#pragma unroll
  for (int mi = 0; mi < 2; mi++)
#pragma unroll
    for (int nj = 0; nj < 2; nj++)
#pragma unroll
      for (int i = 0; i < 4; i++) {
        int row = bm + wr * 32 + mi * 16 + lg * 4 + i;
        int col = bn + wc * 32 + nj * 16 + lr;
        out[(size_t)row * N + col] =
            acc[mi][nj][i] + bias[col] + resid[(size_t)row * N + col];
      }
}

// ---------------- flash attention: 4-wave blocks, 3-buffer counted-vmcnt
//                  pipeline (T3/T4), LDS K/V, register P ---------------------
__global__ __launch_bounds__(256) void attn_kernel(
    const short* __restrict__ qb, const short* __restrict__ k_tiled,
    const _Float16* __restrict__ v_tiled, short* __restrict__ attn_out) {
  const int S = 2048, HD = 64;
  int h = blockIdx.x;
  int qblk = blockIdx.y;
  int tid = threadIdx.x;
  int w = tid >> 6, l = tid & 63;
  int lr = l & 15, lg = l >> 4;
  int q0 = qblk * 64 + w * 16;

  __shared__ __align__(16) short Kl[3][64][64];
  __shared__ __align__(16) _Float16 Vl[3][64][64];

  const short* qptr = qb + ((size_t)h * S + q0 + lr) * HD;
  short8 qf0 = *(const short8*)(qptr + lg * 8);
  short8 qf1 = *(const short8*)(qptr + 32 + lg * 8);

  // 4 async16 per wave per tile (counts 4 on vmcnt)
  auto stageKV = [&](int b, int kt) {
    const short* gk = k_tiled + (((size_t)h * 32 + kt) << 12) + tid * 8;
    const _Float16* gv = v_tiled + (((size_t)h * 32 + kt) << 12) + tid * 8;
    char* lk = (char*)&Kl[b][0][0] + w * 1024;
    char* lv = (char*)&Vl[b][0][0] + w * 1024;
    async16(lk, gk);
    async16(lk + 4096, gk + 2048);
    async16(lv, gv);
    async16(lv + 4096, gv + 2048);
  };

  float m = -1e30f, lsum = 0.f;  // lsum: per-lane partial (reduced at end)
  f32x4 oacc[4] = {};            // O[q=lg*4+i][dv=nb*16+lr]

  auto compute_tile = [&](int buf) {
    const short* Kb = &Kl[buf][0][0];
    const _Float16* Vb = &Vl[buf][0][0];
    f32x4 st[4];
    __builtin_amdgcn_s_setprio(1);
#pragma unroll
    for (int kk = 0; kk < 4; kk++) {
      int r = kk * 16 + lr;
      int sw = r & 7;
      short8 kf0 = *(const short8*)(Kb + r * 64 + ((lg ^ sw) << 3));
      short8 kf1 = *(const short8*)(Kb + r * 64 + (((4 + lg) ^ sw) << 3));
      f32x4 s0 = {};
      s0 = mfma16(kf0, qf0, s0);
      s0 = mfma16(kf1, qf1, s0);
      st[kk] = s0;
    }
    __builtin_amdgcn_s_setprio(0);
    // per-lane partial max is sufficient for the defer check:
    // true row max = max over lanes' pmax, so __all(pmax<=m+8) bounds it.
    float m0 = fmaxf(fmaxf(st[0][0], st[0][1]), fmaxf(st[0][2], st[0][3]));
    float m1 = fmaxf(fmaxf(st[1][0], st[1][1]), fmaxf(st[1][2], st[1][3]));
    float m2 = fmaxf(fmaxf(st[2][0], st[2][1]), fmaxf(st[2][2], st[2][3]));
    float m3 = fmaxf(fmaxf(st[3][0], st[3][1]), fmaxf(st[3][2], st[3][3]));
    float pmax = fmaxf(fmaxf(m0, m1), fmaxf(m2, m3));
    if (!__all(pmax <= m + 8.0f)) {  // defer-rescale (T13); rare path
      float tm = pmax;
      tm = fmaxf(tm, __shfl_xor(tm, 16));
      tm = fmaxf(tm, __shfl_xor(tm, 32));
      float mnew = fmaxf(m, tm);
      float fac = __builtin_amdgcn_exp2f(m - mnew);
      lsum *= fac;
#pragma unroll
      for (int i = 0; i < 4; i++) {
        float fi = __shfl(fac, lg * 4 + i);
#pragma unroll
        for (int nb = 0; nb < 4; nb++) oacc[nb][i] *= fi;
      }
      m = mnew;
    }
    half4 pf[4];
    float ps[4];
#pragma unroll
    for (int kk = 0; kk < 4; kk++) {
      float p0 = __builtin_amdgcn_exp2f(st[kk][0] - m);
      float p1 = __builtin_amdgcn_exp2f(st[kk][1] - m);
      float p2 = __builtin_amdgcn_exp2f(st[kk][2] - m);
      float p3 = __builtin_amdgcn_exp2f(st[kk][3] - m);
      half2v lo = __builtin_bit_cast(half2v, __builtin_amdgcn_cvt_pkrtz(p0, p1));
      half2v hi = __builtin_bit_cast(half2v, __builtin_amdgcn_cvt_pkrtz(p2, p3));
      pf[kk][0] = lo[0]; pf[kk][1] = lo[1];
      pf[kk][2] = hi[0]; pf[kk][3] = hi[1];
      ps[kk] = (p0 + p1) + (p2 + p3);
    }
    lsum += (ps[0] + ps[1]) + (ps[2] + ps[3]);
#pragma unroll
    for (int kk = 0; kk < 4; kk++) {
      half4 vf[4];
#pragma unroll
      for (int nb = 0; nb < 4; nb++) {
        int dv = nb * 16 + lr;
        vf[nb] = *(const half4*)(Vb + dv * 64 + ((((kk << 2) + lg) ^ lr) << 2));
      }
      __builtin_amdgcn_s_setprio(1);
#pragma unroll
      for (int nb = 0; nb < 4; nb++)
        oacc[nb] = __builtin_amdgcn_mfma_f32_16x16x16f16(pf[kk], vf[nb], oacc[nb], 0, 0, 0);
      __builtin_amdgcn_s_setprio(0);
    }
  };

  // 3-deep pipeline: stage t issued 2 tiles ahead; barrier never drains vmcnt0.
  stageKV(0, 0);
  stageKV(1, 1);
  for (int t = 0; t < 32; ++t) {
    // drain tile t's 4 loads; leave tile t+1's in flight
    if (t < 31) {
      asm volatile("s_waitcnt vmcnt(4)" ::: "memory");
    } else {
      asm volatile("s_waitcnt vmcnt(0)" ::: "memory");
    }
    __builtin_amdgcn_sched_barrier(0);
    __builtin_amdgcn_s_barrier();
    __builtin_amdgcn_sched_barrier(0);
    // all waves done reading buffer (t-1)%3 -> safe to overwrite with t+2
    if (t + 2 < 32) stageKV((t + 2) % 3, t + 2);
    compute_tile(t % 3);
  }

  // final cross-lane row-sum reduce (deferred from per-tile)
  lsum += __shfl_xor(lsum, 16);
  lsum += __shfl_xor(lsum, 32);

#pragma unroll
  for (int i = 0; i < 4; i++) {
    float li = __shfl(lsum, lg * 4 + i);
    float inv = 1.0f / li;
    int row = q0 + lg * 4 + i;
#pragma unroll
    for (int nb = 0; nb < 4; nb++)
      attn_out[(size_t)row * 1280 + h * 64 + nb * 16 + lr] = f2bf(oacc[nb][i] * inv);
  }
}

// ---------------- launch ----------------

extern "C" void kernel_launch(void* const* d_in, const int* in_sizes, int n_in,
                              void* d_out, int out_size, void* d_ws, size_t ws_size,
                              hipStream_t stream) {
  const float* hs = (const float*)d_in[0];
  const float* p_out = (const float*)d_in[1];
  const float* p_inv = (const float*)d_in[2];
  const float* Wq = (const float*)d_in[3];
  const float* Wk = (const float*)d_in[4];
  const float* Wv = (const float*)d_in[5];
  const float* Wo = (const float*)d_in[6];
  const float* bo = (const float*)d_in[7];
  float* out = (float*)d_out;
  char* ws = (char*)d_ws;

  // workspace layout (bytes)
  short* hs_bf = (short*)(ws + 0);                  //  5,242,880
  short* BT0 = (short*)(ws + 5242880);              //  9,830,400
  short* BT1 = (short*)(ws + 15073280);             //  9,830,400
  short* wo_t = (short*)(ws + 24903680);            //  3,276,800
  short* q_bf = (short*)(ws + 28180480);            //  5,242,880
  short* k_tiled = (short*)(ws + 33423360);         //  5,242,880
  _Float16* v_tiled = (_Float16*)(ws + 38666240);   //  5,242,880
  short* attn_bf = (short*)(ws + 43909120);         //  5,242,880 (ends 49,152,000)

  const float QSCALE = 0.125f * 1.44269504f;  // hd^-0.5 * log2(e)

  capeT_all_kernel<<<dim3(40, 40, 5), dim3(32, 8), 0, stream>>>(
      Wq, Wk, Wv, Wo, p_inv, p_out, QSCALE, BT0, BT1, wo_t, hs, hs_bf);

  gemm128_qkv_kernel<<<dim3(30, 16), 256, 0, stream>>>(
      hs_bf, BT0, BT1, 2048, 3840, 1280, q_bf, k_tiled, v_tiled);

  attn_kernel<<<dim3(20, 32), 256, 0, stream>>>(q_bf, k_tiled, v_tiled, attn_bf);

  gemm64_o_kernel<<<dim3(20, 32), 256, 0, stream>>>(
      attn_bf, wo_t, 2048, 1280, 1280, bo, hs, out);
}